// Round 1
// baseline (1994.342 us; speedup 1.0000x reference)
//
#include <hip/hip_runtime.h>
#include <stdint.h>
#include <math.h>

// ---- problem constants ----
#define NB 32
#define NH 256
#define NW 256
#define HW 65536
#define NJ 8
#define NCHAN 9           // 1 det channel + 8 joint channels per batch
#define NCH 288           // NB * NCHAN
#define TOPK 100
#define THRESH_C 0.1f
#define NEG_C (-10000.0f)

// ---- output layout (float offsets), concat of reference return tuple ----
#define OUT_BBOX  0       // (32,100,4)   12800
#define OUT_SCORE 12800   // (32,100,1)    3200
#define OUT_KPS   16000   // (32,100,16)  51200
#define OUT_CLS   67200   // (32,100,1)    3200
#define OUT_SCALE 70400   // (32,100,3)    9600
#define OUT_DISP  80000   // (32,100,16)  51200
#define OUT_HEAT  131200  // (32,100,16)  51200
// total 182400

// monotone float->uint key (order-preserving, incl. negatives)
__device__ __forceinline__ uint32_t flip_key(uint32_t b) {
    return (b & 0x80000000u) ? ~b : (b | 0x80000000u);
}
__device__ __forceinline__ float key_to_float(uint32_t k) {
    uint32_t b = (k & 0x80000000u) ? (k & 0x7FFFFFFFu) : ~k;
    return __uint_as_float(b);
}
__device__ __forceinline__ float sigmoidf_(float x) {
    return 1.0f / (1.0f + expf(-x));
}

__global__ void zero_counters(uint32_t* c) {
    int i = blockIdx.x * blockDim.x + threadIdx.x;
    if (i < NCH) c[i] = 0;
}

// NMS in RAW space (monotone-equivalent to sigmoid space); compact survivors.
__global__ void nms_compact(const float* __restrict__ hm,
                            const float* __restrict__ hm_hp,
                            uint32_t* __restrict__ counters,
                            uint2* __restrict__ buf, int cap) {
    int tid = blockIdx.x * blockDim.x + threadIdx.x;   // exact grid: NCH*HW
    int ch  = tid >> 16;
    int pix = tid & 0xFFFF;
    int b = ch / NCHAN, c = ch % NCHAN;
    const float* __restrict__ src = (c == 0)
        ? (hm + (size_t)b * HW)
        : (hm_hp + ((size_t)b * NJ + (c - 1)) * HW);
    int y = pix >> 8, x = pix & 255;
    int ym = (y > 0) ? y - 1 : 0, yp = (y < NH - 1) ? y + 1 : NH - 1;
    int xm = (x > 0) ? x - 1 : 0, xp = (x < NW - 1) ? x + 1 : NW - 1;
    float v = src[pix];
    // clamped 3x3 max == 'SAME' window max (clamped coords stay inside window)
    float m = v;
    m = fmaxf(m, src[ym * NW + xm]); m = fmaxf(m, src[ym * NW + x]); m = fmaxf(m, src[ym * NW + xp]);
    m = fmaxf(m, src[y  * NW + xm]);                                 m = fmaxf(m, src[y  * NW + xp]);
    m = fmaxf(m, src[yp * NW + xm]); m = fmaxf(m, src[yp * NW + x]); m = fmaxf(m, src[yp * NW + xp]);
    bool surv = (v >= m);
    unsigned long long mask = __ballot(surv);
    int lane = threadIdx.x & 63;
    int total = __popcll(mask);
    unsigned base = 0;
    if (lane == 0 && total) base = atomicAdd(&counters[ch], (uint32_t)total);
    base = (unsigned)__shfl((int)base, 0);
    if (surv) {
        unsigned pos = base + (unsigned)__popcll(mask & ((1ull << lane) - 1ull));
        if (pos < (unsigned)cap)
            buf[(size_t)ch * cap + pos] = make_uint2(flip_key(__float_as_uint(v)), (unsigned)pix);
    }
}

// exact per-channel top-K (value desc, index asc) via byte-radix select + bitonic sort
__global__ void select_topk(const uint2* __restrict__ buf,
                            const uint32_t* __restrict__ counters, int cap,
                            float* __restrict__ det_score, int* __restrict__ det_ind,
                            float* __restrict__ hp_score, int* __restrict__ hp_ind) {
    int ch = blockIdx.x;
    int n = (int)min(counters[ch], (uint32_t)cap);
    const uint2* __restrict__ d = buf + (size_t)ch * cap;

    __shared__ uint32_t hist[256];
    __shared__ int sKrem;
    __shared__ uint32_t sMask, sPref;
    __shared__ uint2 cand[TOPK];
    __shared__ uint32_t tieIdx[512];
    __shared__ int gcnt, tcnt;
    __shared__ uint64_t keys[128];

    if (threadIdx.x == 0) { sKrem = TOPK; sMask = 0; sPref = 0; }
    __syncthreads();

    for (int shift = 24; shift >= 0; shift -= 8) {
        for (int i = threadIdx.x; i < 256; i += blockDim.x) hist[i] = 0;
        __syncthreads();
        uint32_t pm = sMask, pv = sPref;
        for (int i = threadIdx.x; i < n; i += blockDim.x) {
            uint32_t vb = d[i].x;
            if ((vb & pm) == pv) atomicAdd(&hist[(vb >> shift) & 0xFF], 1u);
        }
        __syncthreads();
        if (threadIdx.x == 0) {
            int rem = sKrem, cum = 0, bin = 255;
            for (; bin >= 0; --bin) {
                int h = (int)hist[bin];
                if (cum + h >= rem) break;
                cum += h;
            }
            if (bin < 0) bin = 0;  // n < K fallback (cannot happen with this data)
            sKrem = rem - cum;
            sPref = pv | ((uint32_t)bin << shift);
            sMask = pm | (0xFFu << shift);
        }
        __syncthreads();
    }
    uint32_t T = sPref;
    int tiesNeeded = sKrem;            // >= 1
    if (threadIdx.x == 0) { gcnt = 0; tcnt = 0; }
    __syncthreads();

    for (int i = threadIdx.x; i < n; i += blockDim.x) {
        uint2 e = d[i];
        if (e.x > T) { int p = atomicAdd(&gcnt, 1); if (p < TOPK) cand[p] = e; }
        else if (e.x == T) { int p = atomicAdd(&tcnt, 1); if (p < 512) tieIdx[p] = e.y; }
    }
    __syncthreads();
    int g  = min(gcnt, TOPK);          // == TOPK - tiesNeeded by construction
    int tc = min(tcnt, 512);

    for (int i = threadIdx.x; i < 128; i += blockDim.x) keys[i] = 0;
    __syncthreads();
    // greater-than-threshold entries
    for (int i = threadIdx.x; i < g; i += blockDim.x)
        keys[i] = ((uint64_t)cand[i].x << 32) | (uint64_t)(0xFFFFFFFFu - cand[i].y);
    // tie entries: take the tiesNeeded smallest indices (jax lower-index-first)
    for (int i = threadIdx.x; i < tc; i += blockDim.x) {
        uint32_t my = tieIdx[i];
        int r = 0;
        for (int m2 = 0; m2 < tc; ++m2) r += (tieIdx[m2] < my) ? 1 : 0;
        if (r < tiesNeeded)
            keys[g + r] = ((uint64_t)T << 32) | (uint64_t)(0xFFFFFFFFu - my);
    }
    __syncthreads();

    // bitonic sort 128 keys descending (composite: value desc, index asc)
    for (int len = 2; len <= 128; len <<= 1) {
        for (int stride = len >> 1; stride > 0; stride >>= 1) {
            int i = threadIdx.x;
            if (i < 128) {
                int j2 = i ^ stride;
                if (j2 > i) {
                    uint64_t a = keys[i], c2 = keys[j2];
                    bool desc = ((i & len) == 0);
                    bool sw = desc ? (a < c2) : (a > c2);
                    if (sw) { keys[i] = c2; keys[j2] = a; }
                }
            }
            __syncthreads();
        }
    }

    int b = ch / NCHAN, c = ch % NCHAN;
    for (int k = threadIdx.x; k < TOPK; k += blockDim.x) {
        uint64_t key = keys[k];
        float raw = key_to_float((uint32_t)(key >> 32));
        int idx = (int)(0xFFFFFFFFu - (uint32_t)key);
        float s = sigmoidf_(raw);
        if (c == 0) { det_score[b * TOPK + k] = s; det_ind[b * TOPK + k] = idx; }
        else {
            int o = (b * NJ + (c - 1)) * TOPK + k;
            hp_score[o] = s; hp_ind[o] = idx;
        }
    }
}

// per (b,j,l): heatmap keypoint candidates with offset + threshold masking
__global__ void kp_candidates(const float* __restrict__ hp_offset,
                              const float* __restrict__ hp_score,
                              const int* __restrict__ hp_ind,
                              float* __restrict__ hm_x, float* __restrict__ hm_y,
                              float* __restrict__ hm_sc) {
    int tid = blockIdx.x * blockDim.x + threadIdx.x;
    if (tid >= NB * NJ * TOPK) return;
    int bj = tid / TOPK;
    int b = bj / NJ;
    int ind = hp_ind[tid];
    float sc = hp_score[tid];
    float x = (float)(ind & 255) + hp_offset[((size_t)b * 2 + 0) * HW + ind];
    float y = (float)(ind >> 8)  + hp_offset[((size_t)b * 2 + 1) * HW + ind];
    bool m = sc > THRESH_C;
    hm_sc[tid] = m ? sc : -1.0f;
    hm_x[tid]  = m ? x  : NEG_C;
    hm_y[tid]  = m ? y  : NEG_C;
}

// per (b,k): bbox / score / cls / scale / kps_displacement
__global__ void det_decode(const float* __restrict__ wh, const float* __restrict__ kps,
                           const float* __restrict__ reg, const float* __restrict__ scale,
                           const float* __restrict__ det_score, const int* __restrict__ det_ind,
                           float* __restrict__ out) {
    int tid = blockIdx.x * blockDim.x + threadIdx.x;
    if (tid >= NB * TOPK) return;
    int b = tid / TOPK;
    int ind = det_ind[tid];
    float xs = (float)(ind & 255), ys = (float)(ind >> 8);
    float r0 = reg[((size_t)b * 2 + 0) * HW + ind];
    float r1 = reg[((size_t)b * 2 + 1) * HW + ind];
    float xr = xs + r0, yr = ys + r1;
    float w0 = wh[((size_t)b * 2 + 0) * HW + ind];
    float w1 = wh[((size_t)b * 2 + 1) * HW + ind];
    float* bb = out + OUT_BBOX + (size_t)tid * 4;
    bb[0] = xr - w0 * 0.5f;
    bb[1] = yr - w1 * 0.5f;
    bb[2] = xr + w0 * 0.5f;
    bb[3] = yr + w1 * 0.5f;
    out[OUT_SCORE + tid] = det_score[tid];
    out[OUT_CLS + tid] = 0.0f;                 // clses = ind // K over c=1 -> always 0
    float* os = out + OUT_SCALE + (size_t)tid * 3;
    os[0] = scale[((size_t)b * 3 + 0) * HW + ind];
    os[1] = scale[((size_t)b * 3 + 1) * HW + ind];
    os[2] = scale[((size_t)b * 3 + 2) * HW + ind];
    float* kd = out + OUT_DISP + (size_t)tid * 16;
#pragma unroll
    for (int j = 0; j < NJ; ++j) {
        kd[2 * j]     = kps[((size_t)b * 16 + 2 * j)     * HW + ind] + xs;
        kd[2 * j + 1] = kps[((size_t)b * 16 + 2 * j + 1) * HW + ind] + ys;
    }
}

// per (b,k,j): nearest heatmap candidate, masks, final kps outputs
__global__ void joint_assign(const float* __restrict__ hm_x, const float* __restrict__ hm_y,
                             const float* __restrict__ hm_sc, float* __restrict__ out) {
    int b = blockIdx.x;
    __shared__ float sx[NJ * TOPK], sy[NJ * TOPK], ss[NJ * TOPK];
    for (int i = threadIdx.x; i < NJ * TOPK; i += blockDim.x) {
        sx[i] = hm_x[b * NJ * TOPK + i];
        sy[i] = hm_y[b * NJ * TOPK + i];
        ss[i] = hm_sc[b * NJ * TOPK + i];
    }
    __syncthreads();
    for (int w = threadIdx.x; w < TOPK * NJ; w += blockDim.x) {
        int k = w >> 3, j = w & 7;
        int tk = b * TOPK + k;
        float kx = out[OUT_DISP + (size_t)tk * 16 + 2 * j];
        float ky = out[OUT_DISP + (size_t)tk * 16 + 2 * j + 1];
        const float* bb = out + OUT_BBOX + (size_t)tk * 4;
        float x0 = bb[0], y0 = bb[1], x1 = bb[2], y1 = bb[3];
        float best = 1e30f; int bl = 0;
        for (int l = 0; l < TOPK; ++l) {
            float dx = kx - sx[j * TOPK + l];
            float dy = ky - sy[j * TOPK + l];
            float dist = sqrtf(dx * dx + dy * dy);
            if (dist < best) { best = dist; bl = l; }  // strict <: first-min == argmin
        }
        float hx = sx[j * TOPK + bl], hy = sy[j * TOPK + bl], hs = ss[j * TOPK + bl];
        float diag = fmaxf(y1 - y0, x1 - x0);
        bool mask = (hx < x0) || (hx > x1) || (hy < y0) || (hy > y1) ||
                    (hs < THRESH_C) || (best > diag * 0.3f);
        out[OUT_KPS + (size_t)tk * 16 + 2 * j]     = mask ? kx : hx;
        out[OUT_KPS + (size_t)tk * 16 + 2 * j + 1] = mask ? ky : hy;
        float sc = out[OUT_SCORE + tk];
        bool mask2 = (hx > 0.8f * x0) && (hx < 1.2f * x1) && (hy > 0.8f * y0) &&
                     (hy < 1.2f * y1) && (hs > THRESH_C) && (best < diag * 0.5f) &&
                     (sc > THRESH_C);
        float fx = mask2 ? hx : NEG_C;
        float fy = mask2 ? hy : NEG_C;
        bool valid = (fx != NEG_C) && (fy != NEG_C);
        out[OUT_HEAT + (size_t)tk * 16 + 2 * j]     = valid ? fx : NEG_C;
        out[OUT_HEAT + (size_t)tk * 16 + 2 * j + 1] = valid ? fy : NEG_C;
    }
}

extern "C" void kernel_launch(void* const* d_in, const int* in_sizes, int n_in,
                              void* d_out, int out_size, void* d_ws, size_t ws_size,
                              hipStream_t stream) {
    const float* hm        = (const float*)d_in[0];
    const float* wh        = (const float*)d_in[1];
    const float* kps       = (const float*)d_in[2];
    const float* reg       = (const float*)d_in[3];
    const float* hm_hp     = (const float*)d_in[4];
    const float* hp_offset = (const float*)d_in[5];
    const float* scale     = (const float*)d_in[6];
    float* out = (float*)d_out;
    char* ws = (char*)d_ws;

    // workspace layout (bytes)
    uint32_t* counters = (uint32_t*)ws;                 // 288*4, padded to 4096
    float* det_score = (float*)(ws + 4096);             // 3200 f
    int*   det_ind   = (int*)(ws + 4096 + 12800);       // 3200 i
    float* hp_score  = (float*)(ws + 29696);            // 25600 f
    int*   hp_ind    = (int*)(ws + 132096);             // 25600 i
    float* hm_x      = (float*)(ws + 234496);           // 25600 f
    float* hm_y      = (float*)(ws + 336896);           // 25600 f
    float* hm_sc     = (float*)(ws + 439296);           // 25600 f
    const size_t fixed = 541696;
    size_t cap_avail = (ws_size > fixed) ? (ws_size - fixed) / (sizeof(uint2) * NCH) : 0;
    int cap = (int)((cap_avail < 16384) ? cap_avail : 16384);  // expect ~7281 survivors/channel
    if (cap < 1) cap = 1;
    uint2* buf = (uint2*)(ws + fixed);

    zero_counters<<<2, 256, 0, stream>>>(counters);
    nms_compact<<<(NCH * HW) / 256, 256, 0, stream>>>(hm, hm_hp, counters, buf, cap);
    select_topk<<<NCH, 256, 0, stream>>>(buf, counters, cap, det_score, det_ind, hp_score, hp_ind);
    kp_candidates<<<(NB * NJ * TOPK + 255) / 256, 256, 0, stream>>>(hp_offset, hp_score, hp_ind, hm_x, hm_y, hm_sc);
    det_decode<<<(NB * TOPK + 255) / 256, 256, 0, stream>>>(wh, kps, reg, scale, det_score, det_ind, out);
    joint_assign<<<NB, 256, 0, stream>>>(hm_x, hm_y, hm_sc, out);
}

// Round 2
// 379.640 us; speedup vs baseline: 5.2532x; 5.2532x over previous
//
#include <hip/hip_runtime.h>
#include <stdint.h>
#include <math.h>

// ---- problem constants ----
#define NB 32
#define NH 256
#define NW 256
#define HW 65536
#define NJ 8
#define NCHAN 9           // 1 det channel + 8 joint channels per batch
#define NCH 288           // NB * NCHAN
#define TOPK 100
#define THRESH_C 0.1f
#define NEG_C (-10000.0f)
#define CTR_STRIDE 16     // counters padded to 64B to kill cacheline contention

// ---- output layout (float offsets), concat of reference return tuple ----
#define OUT_BBOX  0       // (32,100,4)   12800
#define OUT_SCORE 12800   // (32,100,1)    3200
#define OUT_KPS   16000   // (32,100,16)  51200
#define OUT_CLS   67200   // (32,100,1)    3200
#define OUT_SCALE 70400   // (32,100,3)    9600
#define OUT_DISP  80000   // (32,100,16)  51200
#define OUT_HEAT  131200  // (32,100,16)  51200
// total 182400

// monotone float->uint key (order-preserving, incl. negatives)
__device__ __forceinline__ uint32_t flip_key(uint32_t b) {
    return (b & 0x80000000u) ? ~b : (b | 0x80000000u);
}
__device__ __forceinline__ float key_to_float(uint32_t k) {
    uint32_t b = (k & 0x80000000u) ? (k & 0x7FFFFFFFu) : ~k;
    return __uint_as_float(b);
}
__device__ __forceinline__ float sigmoidf_(float x) {
    return 1.0f / (1.0f + expf(-x));
}

__global__ void zero_counters(uint32_t* c) {
    int i = blockIdx.x * blockDim.x + threadIdx.x;
    if (i < NCH * CTR_STRIDE) c[i] = 0;
}

// NMS in RAW space (monotone-equivalent to sigmoid space); compact survivors.
// Block = 256 threads = 4 row-waves; each thread handles 4 consecutive pixels
// (float4). Block covers a 4-row strip of one channel. ONE device atomic per
// block (vs per wave before) — kills the L2 atomic serialization.
__global__ void nms_compact(const float* __restrict__ hm,
                            const float* __restrict__ hm_hp,
                            uint32_t* __restrict__ counters,
                            uint2* __restrict__ buf, int cap) {
    int bid = blockIdx.x;                 // grid = NCH * 64
    int ch = bid >> 6;
    int strip = bid & 63;                 // 4-row strip within channel
    int b = ch / NCHAN, c = ch % NCHAN;
    const float* __restrict__ src = (c == 0)
        ? (hm + (size_t)b * HW)
        : (hm_hp + ((size_t)b * NJ + (c - 1)) * HW);

    int lr   = threadIdx.x >> 6;          // local row 0..3 (== wave id)
    int lane = threadIdx.x & 63;          // 64 col-groups of 4 px
    int y  = strip * 4 + lr;
    int ym = (y > 0) ? y - 1 : 0;
    int yp = (y < NH - 1) ? y + 1 : NH - 1;
    int xb = lane * 4;

    float4 A = ((const float4*)(src + (size_t)ym * NW))[lane];  // row above
    float4 C = ((const float4*)(src + (size_t)y  * NW))[lane];  // center row
    float4 Bm = ((const float4*)(src + (size_t)yp * NW))[lane]; // row below

    // vertical max per column
    float vm0 = fmaxf(fmaxf(A.x, C.x), Bm.x);
    float vm1 = fmaxf(fmaxf(A.y, C.y), Bm.y);
    float vm2 = fmaxf(fmaxf(A.z, C.z), Bm.z);
    float vm3 = fmaxf(fmaxf(A.w, C.w), Bm.w);

    // edge columns from neighbor lanes (64 lanes == one wave == one row)
    float fromLeft  = __shfl(vm3, (lane + 63) & 63);
    float fromRight = __shfl(vm0, (lane + 1) & 63);
    if (lane == 0)  fromLeft  = vm0;   // x=0 clamps to itself
    if (lane == 63) fromRight = vm3;   // x=255 clamps to itself

    float h0 = fmaxf(fromLeft, fmaxf(vm0, vm1));
    float h1 = fmaxf(vm0, fmaxf(vm1, vm2));
    float h2 = fmaxf(vm1, fmaxf(vm2, vm3));
    float h3 = fmaxf(vm2, fmaxf(vm3, fromRight));

    bool s0 = (C.x >= h0), s1 = (C.y >= h1), s2 = (C.z >= h2), s3 = (C.w >= h3);
    int cnt = (int)s0 + (int)s1 + (int)s2 + (int)s3;

    __shared__ uint2 stage[1024];
    __shared__ int blk_cnt;
    __shared__ unsigned gbase_sh;
    if (threadIdx.x == 0) blk_cnt = 0;
    __syncthreads();

    int base = 0;
    if (cnt) base = atomicAdd(&blk_cnt, cnt);   // LDS atomic — cheap
    int p = base;
    int rowoff = y * NW + xb;
    if (s0) stage[p++] = make_uint2(flip_key(__float_as_uint(C.x)), (unsigned)(rowoff + 0));
    if (s1) stage[p++] = make_uint2(flip_key(__float_as_uint(C.y)), (unsigned)(rowoff + 1));
    if (s2) stage[p++] = make_uint2(flip_key(__float_as_uint(C.z)), (unsigned)(rowoff + 2));
    if (s3) stage[p++] = make_uint2(flip_key(__float_as_uint(C.w)), (unsigned)(rowoff + 3));
    __syncthreads();

    int total = blk_cnt;
    if (threadIdx.x == 0)
        gbase_sh = total ? atomicAdd(&counters[ch * CTR_STRIDE], (uint32_t)total) : 0u;
    __syncthreads();
    unsigned gbase = gbase_sh;
    uint2* __restrict__ dst = buf + (size_t)ch * cap;
    for (int i = threadIdx.x; i < total; i += 256) {
        unsigned pos = gbase + (unsigned)i;
        if (pos < (unsigned)cap) dst[pos] = stage[i];
    }
}

// exact per-channel top-K (value desc, index asc) via byte-radix select + bitonic sort
__global__ void select_topk(const uint2* __restrict__ buf,
                            const uint32_t* __restrict__ counters, int cap,
                            float* __restrict__ det_score, int* __restrict__ det_ind,
                            float* __restrict__ hp_score, int* __restrict__ hp_ind) {
    int ch = blockIdx.x;
    int n = (int)min(counters[ch * CTR_STRIDE], (uint32_t)cap);
    const uint2* __restrict__ d = buf + (size_t)ch * cap;

    __shared__ uint32_t hist[256];
    __shared__ int sKrem;
    __shared__ uint32_t sMask, sPref;
    __shared__ uint2 cand[TOPK];
    __shared__ uint32_t tieIdx[512];
    __shared__ int gcnt, tcnt;
    __shared__ uint64_t keys[128];

    if (threadIdx.x == 0) { sKrem = TOPK; sMask = 0; sPref = 0; }
    __syncthreads();

    for (int shift = 24; shift >= 0; shift -= 8) {
        for (int i = threadIdx.x; i < 256; i += blockDim.x) hist[i] = 0;
        __syncthreads();
        uint32_t pm = sMask, pv = sPref;
        for (int i = threadIdx.x; i < n; i += blockDim.x) {
            uint32_t vb = d[i].x;
            if ((vb & pm) == pv) atomicAdd(&hist[(vb >> shift) & 0xFF], 1u);
        }
        __syncthreads();
        if (threadIdx.x == 0) {
            int rem = sKrem, cum = 0, bin = 255;
            for (; bin >= 0; --bin) {
                int h = (int)hist[bin];
                if (cum + h >= rem) break;
                cum += h;
            }
            if (bin < 0) bin = 0;  // n < K fallback (cannot happen with this data)
            sKrem = rem - cum;
            sPref = pv | ((uint32_t)bin << shift);
            sMask = pm | (0xFFu << shift);
        }
        __syncthreads();
    }
    uint32_t T = sPref;
    int tiesNeeded = sKrem;            // >= 1
    if (threadIdx.x == 0) { gcnt = 0; tcnt = 0; }
    __syncthreads();

    for (int i = threadIdx.x; i < n; i += blockDim.x) {
        uint2 e = d[i];
        if (e.x > T) { int p = atomicAdd(&gcnt, 1); if (p < TOPK) cand[p] = e; }
        else if (e.x == T) { int p = atomicAdd(&tcnt, 1); if (p < 512) tieIdx[p] = e.y; }
    }
    __syncthreads();
    int g  = min(gcnt, TOPK);          // == TOPK - tiesNeeded by construction
    int tc = min(tcnt, 512);

    for (int i = threadIdx.x; i < 128; i += blockDim.x) keys[i] = 0;
    __syncthreads();
    // greater-than-threshold entries
    for (int i = threadIdx.x; i < g; i += blockDim.x)
        keys[i] = ((uint64_t)cand[i].x << 32) | (uint64_t)(0xFFFFFFFFu - cand[i].y);
    // tie entries: take the tiesNeeded smallest indices (jax lower-index-first)
    for (int i = threadIdx.x; i < tc; i += blockDim.x) {
        uint32_t my = tieIdx[i];
        int r = 0;
        for (int m2 = 0; m2 < tc; ++m2) r += (tieIdx[m2] < my) ? 1 : 0;
        if (r < tiesNeeded)
            keys[g + r] = ((uint64_t)T << 32) | (uint64_t)(0xFFFFFFFFu - my);
    }
    __syncthreads();

    // bitonic sort 128 keys descending (composite: value desc, index asc)
    for (int len = 2; len <= 128; len <<= 1) {
        for (int stride = len >> 1; stride > 0; stride >>= 1) {
            int i = threadIdx.x;
            if (i < 128) {
                int j2 = i ^ stride;
                if (j2 > i) {
                    uint64_t a = keys[i], c2 = keys[j2];
                    bool desc = ((i & len) == 0);
                    bool sw = desc ? (a < c2) : (a > c2);
                    if (sw) { keys[i] = c2; keys[j2] = a; }
                }
            }
            __syncthreads();
        }
    }

    int b = ch / NCHAN, c = ch % NCHAN;
    for (int k = threadIdx.x; k < TOPK; k += blockDim.x) {
        uint64_t key = keys[k];
        float raw = key_to_float((uint32_t)(key >> 32));
        int idx = (int)(0xFFFFFFFFu - (uint32_t)key);
        float s = sigmoidf_(raw);
        if (c == 0) { det_score[b * TOPK + k] = s; det_ind[b * TOPK + k] = idx; }
        else {
            int o = (b * NJ + (c - 1)) * TOPK + k;
            hp_score[o] = s; hp_ind[o] = idx;
        }
    }
}

// per (b,j,l): heatmap keypoint candidates with offset + threshold masking
__global__ void kp_candidates(const float* __restrict__ hp_offset,
                              const float* __restrict__ hp_score,
                              const int* __restrict__ hp_ind,
                              float* __restrict__ hm_x, float* __restrict__ hm_y,
                              float* __restrict__ hm_sc) {
    int tid = blockIdx.x * blockDim.x + threadIdx.x;
    if (tid >= NB * NJ * TOPK) return;
    int bj = tid / TOPK;
    int b = bj / NJ;
    int ind = hp_ind[tid];
    float sc = hp_score[tid];
    float x = (float)(ind & 255) + hp_offset[((size_t)b * 2 + 0) * HW + ind];
    float y = (float)(ind >> 8)  + hp_offset[((size_t)b * 2 + 1) * HW + ind];
    bool m = sc > THRESH_C;
    hm_sc[tid] = m ? sc : -1.0f;
    hm_x[tid]  = m ? x  : NEG_C;
    hm_y[tid]  = m ? y  : NEG_C;
}

// per (b,k): bbox / score / cls / scale / kps_displacement
__global__ void det_decode(const float* __restrict__ wh, const float* __restrict__ kps,
                           const float* __restrict__ reg, const float* __restrict__ scale,
                           const float* __restrict__ det_score, const int* __restrict__ det_ind,
                           float* __restrict__ out) {
    int tid = blockIdx.x * blockDim.x + threadIdx.x;
    if (tid >= NB * TOPK) return;
    int b = tid / TOPK;
    int ind = det_ind[tid];
    float xs = (float)(ind & 255), ys = (float)(ind >> 8);
    float r0 = reg[((size_t)b * 2 + 0) * HW + ind];
    float r1 = reg[((size_t)b * 2 + 1) * HW + ind];
    float xr = xs + r0, yr = ys + r1;
    float w0 = wh[((size_t)b * 2 + 0) * HW + ind];
    float w1 = wh[((size_t)b * 2 + 1) * HW + ind];
    float* bb = out + OUT_BBOX + (size_t)tid * 4;
    bb[0] = xr - w0 * 0.5f;
    bb[1] = yr - w1 * 0.5f;
    bb[2] = xr + w0 * 0.5f;
    bb[3] = yr + w1 * 0.5f;
    out[OUT_SCORE + tid] = det_score[tid];
    out[OUT_CLS + tid] = 0.0f;                 // clses = ind // K over c=1 -> always 0
    float* os = out + OUT_SCALE + (size_t)tid * 3;
    os[0] = scale[((size_t)b * 3 + 0) * HW + ind];
    os[1] = scale[((size_t)b * 3 + 1) * HW + ind];
    os[2] = scale[((size_t)b * 3 + 2) * HW + ind];
    float* kd = out + OUT_DISP + (size_t)tid * 16;
#pragma unroll
    for (int j = 0; j < NJ; ++j) {
        kd[2 * j]     = kps[((size_t)b * 16 + 2 * j)     * HW + ind] + xs;
        kd[2 * j + 1] = kps[((size_t)b * 16 + 2 * j + 1) * HW + ind] + ys;
    }
}

// per (b,k,j): nearest heatmap candidate, masks, final kps outputs
__global__ void joint_assign(const float* __restrict__ hm_x, const float* __restrict__ hm_y,
                             const float* __restrict__ hm_sc, float* __restrict__ out) {
    int b = blockIdx.x;
    __shared__ float sx[NJ * TOPK], sy[NJ * TOPK], ss[NJ * TOPK];
    for (int i = threadIdx.x; i < NJ * TOPK; i += blockDim.x) {
        sx[i] = hm_x[b * NJ * TOPK + i];
        sy[i] = hm_y[b * NJ * TOPK + i];
        ss[i] = hm_sc[b * NJ * TOPK + i];
    }
    __syncthreads();
    for (int w = threadIdx.x; w < TOPK * NJ; w += blockDim.x) {
        int k = w >> 3, j = w & 7;
        int tk = b * TOPK + k;
        float kx = out[OUT_DISP + (size_t)tk * 16 + 2 * j];
        float ky = out[OUT_DISP + (size_t)tk * 16 + 2 * j + 1];
        const float* bb = out + OUT_BBOX + (size_t)tk * 4;
        float x0 = bb[0], y0 = bb[1], x1 = bb[2], y1 = bb[3];
        float best = 1e30f; int bl = 0;
        for (int l = 0; l < TOPK; ++l) {
            float dx = kx - sx[j * TOPK + l];
            float dy = ky - sy[j * TOPK + l];
            float dist = sqrtf(dx * dx + dy * dy);
            if (dist < best) { best = dist; bl = l; }  // strict <: first-min == argmin
        }
        float hx = sx[j * TOPK + bl], hy = sy[j * TOPK + bl], hs = ss[j * TOPK + bl];
        float diag = fmaxf(y1 - y0, x1 - x0);
        bool mask = (hx < x0) || (hx > x1) || (hy < y0) || (hy > y1) ||
                    (hs < THRESH_C) || (best > diag * 0.3f);
        out[OUT_KPS + (size_t)tk * 16 + 2 * j]     = mask ? kx : hx;
        out[OUT_KPS + (size_t)tk * 16 + 2 * j + 1] = mask ? ky : hy;
        float sc = out[OUT_SCORE + tk];
        bool mask2 = (hx > 0.8f * x0) && (hx < 1.2f * x1) && (hy > 0.8f * y0) &&
                     (hy < 1.2f * y1) && (hs > THRESH_C) && (best < diag * 0.5f) &&
                     (sc > THRESH_C);
        float fx = mask2 ? hx : NEG_C;
        float fy = mask2 ? hy : NEG_C;
        bool valid = (fx != NEG_C) && (fy != NEG_C);
        out[OUT_HEAT + (size_t)tk * 16 + 2 * j]     = valid ? fx : NEG_C;
        out[OUT_HEAT + (size_t)tk * 16 + 2 * j + 1] = valid ? fy : NEG_C;
    }
}

extern "C" void kernel_launch(void* const* d_in, const int* in_sizes, int n_in,
                              void* d_out, int out_size, void* d_ws, size_t ws_size,
                              hipStream_t stream) {
    const float* hm        = (const float*)d_in[0];
    const float* wh        = (const float*)d_in[1];
    const float* kps       = (const float*)d_in[2];
    const float* reg       = (const float*)d_in[3];
    const float* hm_hp     = (const float*)d_in[4];
    const float* hp_offset = (const float*)d_in[5];
    const float* scale     = (const float*)d_in[6];
    float* out = (float*)d_out;
    char* ws = (char*)d_ws;

    // workspace layout (bytes)
    uint32_t* counters = (uint32_t*)ws;                 // 288*16*4 = 18432, pad to 32768
    float* det_score = (float*)(ws + 32768);            // 3200 f
    int*   det_ind   = (int*)(ws + 32768 + 12800);      // 3200 i
    float* hp_score  = (float*)(ws + 58368);            // 25600 f
    int*   hp_ind    = (int*)(ws + 160768);             // 25600 i
    float* hm_x      = (float*)(ws + 263168);           // 25600 f
    float* hm_y      = (float*)(ws + 365568);           // 25600 f
    float* hm_sc     = (float*)(ws + 467968);           // 25600 f
    const size_t fixed = 570368;
    size_t cap_avail = (ws_size > fixed) ? (ws_size - fixed) / (sizeof(uint2) * NCH) : 0;
    int cap = (int)((cap_avail < 16384) ? cap_avail : 16384);  // expect ~7281 survivors/channel
    if (cap < 1) cap = 1;
    uint2* buf = (uint2*)(ws + fixed);

    zero_counters<<<(NCH * CTR_STRIDE + 255) / 256, 256, 0, stream>>>(counters);
    nms_compact<<<NCH * 64, 256, 0, stream>>>(hm, hm_hp, counters, buf, cap);
    select_topk<<<NCH, 256, 0, stream>>>(buf, counters, cap, det_score, det_ind, hp_score, hp_ind);
    kp_candidates<<<(NB * NJ * TOPK + 255) / 256, 256, 0, stream>>>(hp_offset, hp_score, hp_ind, hm_x, hm_y, hm_sc);
    det_decode<<<(NB * TOPK + 255) / 256, 256, 0, stream>>>(wh, kps, reg, scale, det_score, det_ind, out);
    joint_assign<<<NB, 256, 0, stream>>>(hm_x, hm_y, hm_sc, out);
}

// Round 3
// 372.127 us; speedup vs baseline: 5.3593x; 1.0202x over previous
//
#include <hip/hip_runtime.h>
#include <stdint.h>
#include <math.h>

// ---- problem constants ----
#define NB 32
#define NH 256
#define NW 256
#define HW 65536
#define NJ 8
#define NCHAN 9           // 1 det channel + 8 joint channels per batch
#define NCH 288           // NB * NCHAN
#define TOPK 100
#define THRESH_C 0.1f
#define NEG_C (-10000.0f)
#define CTR_STRIDE 16     // counters padded to 64B to kill cacheline contention
#define SD_CAP 8064       // survivors staged in LDS (expect ~7281/channel)

// ---- output layout (float offsets), concat of reference return tuple ----
#define OUT_BBOX  0       // (32,100,4)   12800
#define OUT_SCORE 12800   // (32,100,1)    3200
#define OUT_KPS   16000   // (32,100,16)  51200
#define OUT_CLS   67200   // (32,100,1)    3200
#define OUT_SCALE 70400   // (32,100,3)    9600
#define OUT_DISP  80000   // (32,100,16)  51200
#define OUT_HEAT  131200  // (32,100,16)  51200
// total 182400

// monotone float->uint key (order-preserving, incl. negatives)
__device__ __forceinline__ uint32_t flip_key(uint32_t b) {
    return (b & 0x80000000u) ? ~b : (b | 0x80000000u);
}
__device__ __forceinline__ float key_to_float(uint32_t k) {
    uint32_t b = (k & 0x80000000u) ? (k & 0x7FFFFFFFu) : ~k;
    return __uint_as_float(b);
}
__device__ __forceinline__ float sigmoidf_(float x) {
    return 1.0f / (1.0f + expf(-x));
}

// NMS in RAW space (monotone-equivalent to sigmoid space); compact survivors.
// Block = 256 threads = 4 row-waves; each thread 4 px (float4). Block covers a
// 4-row strip. XCD swizzle: blockIdx%8 selects XCD (round-robin dispatch), and
// channel = f(blockIdx%8,...) so all 64 strips of a channel share one XCD's L2
// -> halo rows (rows y-1,y+4 of each strip) are L2 hits instead of HBM refetch.
__global__ void nms_compact(const float* __restrict__ hm,
                            const float* __restrict__ hm_hp,
                            uint32_t* __restrict__ counters,
                            uint2* __restrict__ buf, int cap) {
    int bid = blockIdx.x;                 // grid = NCH * 64 = 18432
    int x8   = bid & 7;                   // XCD under round-robin dispatch
    int s    = bid >> 3;                  // 0..2303 (slot on this XCD)
    int ch   = x8 + 8 * (s >> 6);         // 36 channels per XCD, ch%8 == x8
    int strip = s & 63;                   // 4-row strip within channel
    int b = ch / NCHAN, c = ch % NCHAN;
    const float* __restrict__ src = (c == 0)
        ? (hm + (size_t)b * HW)
        : (hm_hp + ((size_t)b * NJ + (c - 1)) * HW);

    int lr   = threadIdx.x >> 6;          // local row 0..3 (== wave id)
    int lane = threadIdx.x & 63;          // 64 col-groups of 4 px
    int y  = strip * 4 + lr;
    int ym = (y > 0) ? y - 1 : 0;
    int yp = (y < NH - 1) ? y + 1 : NH - 1;
    int xb = lane * 4;

    float4 A = ((const float4*)(src + (size_t)ym * NW))[lane];  // row above
    float4 C = ((const float4*)(src + (size_t)y  * NW))[lane];  // center row
    float4 Bm = ((const float4*)(src + (size_t)yp * NW))[lane]; // row below

    // vertical max per column
    float vm0 = fmaxf(fmaxf(A.x, C.x), Bm.x);
    float vm1 = fmaxf(fmaxf(A.y, C.y), Bm.y);
    float vm2 = fmaxf(fmaxf(A.z, C.z), Bm.z);
    float vm3 = fmaxf(fmaxf(A.w, C.w), Bm.w);

    // edge columns from neighbor lanes (64 lanes == one wave == one row)
    float fromLeft  = __shfl(vm3, (lane + 63) & 63);
    float fromRight = __shfl(vm0, (lane + 1) & 63);
    if (lane == 0)  fromLeft  = vm0;   // x=0 clamps to itself
    if (lane == 63) fromRight = vm3;   // x=255 clamps to itself

    float h0 = fmaxf(fromLeft, fmaxf(vm0, vm1));
    float h1 = fmaxf(vm0, fmaxf(vm1, vm2));
    float h2 = fmaxf(vm1, fmaxf(vm2, vm3));
    float h3 = fmaxf(vm2, fmaxf(vm3, fromRight));

    bool s0 = (C.x >= h0), s1 = (C.y >= h1), s2 = (C.z >= h2), s3 = (C.w >= h3);
    int cnt = (int)s0 + (int)s1 + (int)s2 + (int)s3;

    __shared__ uint2 stage[1024];
    __shared__ int blk_cnt;
    __shared__ unsigned gbase_sh;
    if (threadIdx.x == 0) blk_cnt = 0;
    __syncthreads();

    int base = 0;
    if (cnt) base = atomicAdd(&blk_cnt, cnt);   // LDS atomic — cheap
    int p = base;
    int rowoff = y * NW + xb;
    if (s0) stage[p++] = make_uint2(flip_key(__float_as_uint(C.x)), (unsigned)(rowoff + 0));
    if (s1) stage[p++] = make_uint2(flip_key(__float_as_uint(C.y)), (unsigned)(rowoff + 1));
    if (s2) stage[p++] = make_uint2(flip_key(__float_as_uint(C.z)), (unsigned)(rowoff + 2));
    if (s3) stage[p++] = make_uint2(flip_key(__float_as_uint(C.w)), (unsigned)(rowoff + 3));
    __syncthreads();

    int total = blk_cnt;
    if (threadIdx.x == 0)
        gbase_sh = total ? atomicAdd(&counters[ch * CTR_STRIDE], (uint32_t)total) : 0u;
    __syncthreads();
    unsigned gbase = gbase_sh;
    uint2* __restrict__ dst = buf + (size_t)ch * cap;
    for (int i = threadIdx.x; i < total; i += 256) {
        unsigned pos = gbase + (unsigned)i;
        if (pos < (unsigned)cap) dst[pos] = stage[i];
    }
}

// exact per-channel top-K (value desc, index asc): stage survivors into LDS
// once (single global sweep), then byte-radix select + bitonic sort from LDS.
__global__ void select_topk(const uint2* __restrict__ buf,
                            const uint32_t* __restrict__ counters, int cap,
                            float* __restrict__ det_score, int* __restrict__ det_ind,
                            float* __restrict__ hp_score, int* __restrict__ hp_ind) {
    int ch = blockIdx.x;                  // blockIdx%8 == ch%8 == nms writer's XCD
    int n = (int)min(counters[ch * CTR_STRIDE], (uint32_t)cap);
    const uint2* __restrict__ d = buf + (size_t)ch * cap;
    int nl = (n < SD_CAP) ? n : SD_CAP;   // LDS-resident portion (all, in practice)

    __shared__ uint2 sdat[SD_CAP];        // 63 KB
    __shared__ uint32_t hist[256];
    __shared__ int sKrem;
    __shared__ uint32_t sMask, sPref;
    __shared__ uint2 cand[TOPK];
    __shared__ uint32_t tieIdx[512];
    __shared__ int gcnt, tcnt;
    __shared__ uint64_t keys[128];

    for (int i = threadIdx.x; i < nl; i += blockDim.x) sdat[i] = d[i];
    if (threadIdx.x == 0) { sKrem = TOPK; sMask = 0; sPref = 0; }
    __syncthreads();

    for (int shift = 24; shift >= 0; shift -= 8) {
        for (int i = threadIdx.x; i < 256; i += blockDim.x) hist[i] = 0;
        __syncthreads();
        uint32_t pm = sMask, pv = sPref;
        for (int i = threadIdx.x; i < nl; i += blockDim.x) {
            uint32_t vb = sdat[i].x;
            if ((vb & pm) == pv) atomicAdd(&hist[(vb >> shift) & 0xFF], 1u);
        }
        for (int i = SD_CAP + threadIdx.x; i < n; i += blockDim.x) {   // overflow (rare/never)
            uint32_t vb = d[i].x;
            if ((vb & pm) == pv) atomicAdd(&hist[(vb >> shift) & 0xFF], 1u);
        }
        __syncthreads();
        if (threadIdx.x == 0) {
            int rem = sKrem, cum = 0, bin = 255;
            for (; bin >= 0; --bin) {
                int h = (int)hist[bin];
                if (cum + h >= rem) break;
                cum += h;
            }
            if (bin < 0) bin = 0;  // n < K fallback (cannot happen with this data)
            sKrem = rem - cum;
            sPref = pv | ((uint32_t)bin << shift);
            sMask = pm | (0xFFu << shift);
        }
        __syncthreads();
    }
    uint32_t T = sPref;
    int tiesNeeded = sKrem;            // >= 1
    if (threadIdx.x == 0) { gcnt = 0; tcnt = 0; }
    __syncthreads();

    for (int i = threadIdx.x; i < nl; i += blockDim.x) {
        uint2 e = sdat[i];
        if (e.x > T) { int p = atomicAdd(&gcnt, 1); if (p < TOPK) cand[p] = e; }
        else if (e.x == T) { int p = atomicAdd(&tcnt, 1); if (p < 512) tieIdx[p] = e.y; }
    }
    for (int i = SD_CAP + threadIdx.x; i < n; i += blockDim.x) {
        uint2 e = d[i];
        if (e.x > T) { int p = atomicAdd(&gcnt, 1); if (p < TOPK) cand[p] = e; }
        else if (e.x == T) { int p = atomicAdd(&tcnt, 1); if (p < 512) tieIdx[p] = e.y; }
    }
    __syncthreads();
    int g  = min(gcnt, TOPK);          // == TOPK - tiesNeeded by construction
    int tc = min(tcnt, 512);

    for (int i = threadIdx.x; i < 128; i += blockDim.x) keys[i] = 0;
    __syncthreads();
    // greater-than-threshold entries
    for (int i = threadIdx.x; i < g; i += blockDim.x)
        keys[i] = ((uint64_t)cand[i].x << 32) | (uint64_t)(0xFFFFFFFFu - cand[i].y);
    // tie entries: take the tiesNeeded smallest indices (jax lower-index-first)
    for (int i = threadIdx.x; i < tc; i += blockDim.x) {
        uint32_t my = tieIdx[i];
        int r = 0;
        for (int m2 = 0; m2 < tc; ++m2) r += (tieIdx[m2] < my) ? 1 : 0;
        if (r < tiesNeeded)
            keys[g + r] = ((uint64_t)T << 32) | (uint64_t)(0xFFFFFFFFu - my);
    }
    __syncthreads();

    // bitonic sort 128 keys descending (composite: value desc, index asc)
    for (int len = 2; len <= 128; len <<= 1) {
        for (int stride = len >> 1; stride > 0; stride >>= 1) {
            int i = threadIdx.x;
            if (i < 128) {
                int j2 = i ^ stride;
                if (j2 > i) {
                    uint64_t a = keys[i], c2 = keys[j2];
                    bool desc = ((i & len) == 0);
                    bool sw = desc ? (a < c2) : (a > c2);
                    if (sw) { keys[i] = c2; keys[j2] = a; }
                }
            }
            __syncthreads();
        }
    }

    int b = ch / NCHAN, c = ch % NCHAN;
    for (int k = threadIdx.x; k < TOPK; k += blockDim.x) {
        uint64_t key = keys[k];
        float raw = key_to_float((uint32_t)(key >> 32));
        int idx = (int)(0xFFFFFFFFu - (uint32_t)key);
        float s = sigmoidf_(raw);
        if (c == 0) { det_score[b * TOPK + k] = s; det_ind[b * TOPK + k] = idx; }
        else {
            int o = (b * NJ + (c - 1)) * TOPK + k;
            hp_score[o] = s; hp_ind[o] = idx;
        }
    }
}

// fused tail: kp candidates + det decode + joint assignment. One block per
// batch image; all intermediates (candidates, bboxes, disp, scores) in LDS.
__global__ void decode_tail(const float* __restrict__ wh, const float* __restrict__ kps,
                            const float* __restrict__ reg, const float* __restrict__ scale,
                            const float* __restrict__ hp_offset,
                            const float* __restrict__ det_score, const int* __restrict__ det_ind,
                            const float* __restrict__ hp_score, const int* __restrict__ hp_ind,
                            float* __restrict__ out) {
    int b = blockIdx.x;
    __shared__ float sx[NJ * TOPK], sy[NJ * TOPK], ss[NJ * TOPK];
    __shared__ float kd[TOPK * 16];      // kps_displacement (also OUT_DISP)
    __shared__ float sbb[TOPK * 4];      // bboxes
    __shared__ float ssc[TOPK];          // det scores

    // phase 1: heatmap keypoint candidates (800 per image)
    for (int i = threadIdx.x; i < NJ * TOPK; i += blockDim.x) {
        int t = b * NJ * TOPK + i;
        int ind = hp_ind[t];
        float sc = hp_score[t];
        float x = (float)(ind & 255) + hp_offset[((size_t)b * 2 + 0) * HW + ind];
        float y = (float)(ind >> 8)  + hp_offset[((size_t)b * 2 + 1) * HW + ind];
        bool m = sc > THRESH_C;
        ss[i] = m ? sc : -1.0f;
        sx[i] = m ? x  : NEG_C;
        sy[i] = m ? y  : NEG_C;
    }
    // phase 2a: kps displacement gathers (800 pairs)
    for (int i = threadIdx.x; i < TOPK * NJ; i += blockDim.x) {
        int k = i >> 3, j = i & 7;
        int ind = det_ind[b * TOPK + k];
        float xs = (float)(ind & 255), ys = (float)(ind >> 8);
        kd[k * 16 + 2 * j]     = kps[((size_t)b * 16 + 2 * j)     * HW + ind] + xs;
        kd[k * 16 + 2 * j + 1] = kps[((size_t)b * 16 + 2 * j + 1) * HW + ind] + ys;
    }
    // phase 2b: bbox/score/cls/scale (100 dets)
    for (int k = threadIdx.x; k < TOPK; k += blockDim.x) {
        int tid2 = b * TOPK + k;
        int ind = det_ind[tid2];
        float xs = (float)(ind & 255), ys = (float)(ind >> 8);
        float xr = xs + reg[((size_t)b * 2 + 0) * HW + ind];
        float yr = ys + reg[((size_t)b * 2 + 1) * HW + ind];
        float w0 = wh[((size_t)b * 2 + 0) * HW + ind];
        float w1 = wh[((size_t)b * 2 + 1) * HW + ind];
        float x0 = xr - w0 * 0.5f, y0 = yr - w1 * 0.5f;
        float x1 = xr + w0 * 0.5f, y1 = yr + w1 * 0.5f;
        sbb[k * 4 + 0] = x0; sbb[k * 4 + 1] = y0; sbb[k * 4 + 2] = x1; sbb[k * 4 + 3] = y1;
        float* bb = out + OUT_BBOX + (size_t)tid2 * 4;
        bb[0] = x0; bb[1] = y0; bb[2] = x1; bb[3] = y1;
        float sc = det_score[tid2];
        ssc[k] = sc;
        out[OUT_SCORE + tid2] = sc;
        out[OUT_CLS + tid2] = 0.0f;      // clses = ind // K over c=1 -> always 0
        float* os = out + OUT_SCALE + (size_t)tid2 * 3;
        os[0] = scale[((size_t)b * 3 + 0) * HW + ind];
        os[1] = scale[((size_t)b * 3 + 1) * HW + ind];
        os[2] = scale[((size_t)b * 3 + 2) * HW + ind];
    }
    __syncthreads();
    // write disp from LDS (coalesced)
    for (int i = threadIdx.x; i < TOPK * 16; i += blockDim.x)
        out[OUT_DISP + (size_t)b * TOPK * 16 + i] = kd[i];

    // phase 3: joint assignment (800 work items)
    for (int w = threadIdx.x; w < TOPK * NJ; w += blockDim.x) {
        int k = w >> 3, j = w & 7;
        int tk = b * TOPK + k;
        float kx = kd[k * 16 + 2 * j];
        float ky = kd[k * 16 + 2 * j + 1];
        float x0 = sbb[k * 4 + 0], y0 = sbb[k * 4 + 1];
        float x1 = sbb[k * 4 + 2], y1 = sbb[k * 4 + 3];
        float best = 1e30f; int bl = 0;
        for (int l = 0; l < TOPK; ++l) {
            float dx = kx - sx[j * TOPK + l];
            float dy = ky - sy[j * TOPK + l];
            float dist = sqrtf(dx * dx + dy * dy);
            if (dist < best) { best = dist; bl = l; }  // strict <: first-min == argmin
        }
        float hx = sx[j * TOPK + bl], hy = sy[j * TOPK + bl], hs = ss[j * TOPK + bl];
        float diag = fmaxf(y1 - y0, x1 - x0);
        bool mask = (hx < x0) || (hx > x1) || (hy < y0) || (hy > y1) ||
                    (hs < THRESH_C) || (best > diag * 0.3f);
        out[OUT_KPS + (size_t)tk * 16 + 2 * j]     = mask ? kx : hx;
        out[OUT_KPS + (size_t)tk * 16 + 2 * j + 1] = mask ? ky : hy;
        float sc = ssc[k];
        bool mask2 = (hx > 0.8f * x0) && (hx < 1.2f * x1) && (hy > 0.8f * y0) &&
                     (hy < 1.2f * y1) && (hs > THRESH_C) && (best < diag * 0.5f) &&
                     (sc > THRESH_C);
        float fx = mask2 ? hx : NEG_C;
        float fy = mask2 ? hy : NEG_C;
        bool valid = (fx != NEG_C) && (fy != NEG_C);
        out[OUT_HEAT + (size_t)tk * 16 + 2 * j]     = valid ? fx : NEG_C;
        out[OUT_HEAT + (size_t)tk * 16 + 2 * j + 1] = valid ? fy : NEG_C;
    }
}

extern "C" void kernel_launch(void* const* d_in, const int* in_sizes, int n_in,
                              void* d_out, int out_size, void* d_ws, size_t ws_size,
                              hipStream_t stream) {
    const float* hm        = (const float*)d_in[0];
    const float* wh        = (const float*)d_in[1];
    const float* kps       = (const float*)d_in[2];
    const float* reg       = (const float*)d_in[3];
    const float* hm_hp     = (const float*)d_in[4];
    const float* hp_offset = (const float*)d_in[5];
    const float* scale     = (const float*)d_in[6];
    float* out = (float*)d_out;
    char* ws = (char*)d_ws;

    // workspace layout (bytes)
    uint32_t* counters = (uint32_t*)ws;                 // 288*16*4 = 18432, pad to 32768
    float* det_score = (float*)(ws + 32768);            // 3200 f
    int*   det_ind   = (int*)(ws + 32768 + 12800);      // 3200 i
    float* hp_score  = (float*)(ws + 58368);            // 25600 f
    int*   hp_ind    = (int*)(ws + 160768);             // 25600 i
    const size_t fixed = 263168;
    size_t cap_avail = (ws_size > fixed) ? (ws_size - fixed) / (sizeof(uint2) * NCH) : 0;
    int cap = (int)((cap_avail < 16384) ? cap_avail : 16384);  // expect ~7281 survivors/channel
    if (cap < 1) cap = 1;
    uint2* buf = (uint2*)(ws + fixed);

    hipMemsetAsync(counters, 0, NCH * CTR_STRIDE * sizeof(uint32_t), stream);
    nms_compact<<<NCH * 64, 256, 0, stream>>>(hm, hm_hp, counters, buf, cap);
    select_topk<<<NCH, 256, 0, stream>>>(buf, counters, cap, det_score, det_ind, hp_score, hp_ind);
    decode_tail<<<NB, 256, 0, stream>>>(wh, kps, reg, scale, hp_offset,
                                        det_score, det_ind, hp_score, hp_ind, out);
}